// Round 7
// baseline (662.833 us; speedup 1.0000x reference)
//
#include <hip/hip_runtime.h>

#define T_ 128
#define B_ 4096
#define N_ (T_*B_)
#define H_ 128
#define FEAT_ 96
#define K_ 224
#define G4H_ 512
#define L2E 1.4426950408889634f

typedef __attribute__((ext_vector_type(8))) short short8;   // 8 bf16 = 4 VGPRs
typedef __attribute__((ext_vector_type(4))) short short4v;  // 4 bf16 = 2 VGPRs
typedef __attribute__((ext_vector_type(4))) float f32x4;

// sigmoid of PRE-SCALED gate (weights folded with log2e): 1/(1+2^-x)
__device__ __forceinline__ float sig2(float x) {
    return __builtin_amdgcn_rcpf(1.0f + __builtin_amdgcn_exp2f(-x));
}
// full tanh (for unscaled cell state)
__device__ __forceinline__ float ftanh(float x) {
    float e = __builtin_amdgcn_exp2f(-2.0f * L2E * x);
    return fmaf(2.0f, __builtin_amdgcn_rcpf(1.0f + e), -1.0f);
}
__device__ __forceinline__ short f2bf(float f) {
    unsigned u = __builtin_bit_cast(unsigned, f);
    u += 0x7fff + ((u >> 16) & 1);              // RNE
    return (short)(u >> 16);
}
__device__ __forceinline__ short4v pack4relu(const f32x4 a) {
    short4v v;
    v[0] = f2bf(fmaxf(a[0], 0.f)); v[1] = f2bf(fmaxf(a[1], 0.f));
    v[2] = f2bf(fmaxf(a[2], 0.f)); v[3] = f2bf(fmaxf(a[3], 0.f));
    return v;
}

// feats stored in MFMA-fragment order per 16-sample group:
// featsb[ ((t*256 + b/16)*3 + kk)*512 + L*8 + j ]
#define FBASE(t, grp, kk) ((((size_t)(t) * 256 + (grp)) * 3 + (kk)) * 512)

// ---------------- prep: pack all weights into bf16 MFMA-fragment order ----------------
// LSTM weights/bias pre-scaled: i,f,o gates by log2e; g gate by 2*log2e.
// W1 folded with 1/255 (image normalization).
__global__ __launch_bounds__(256) void prep_kernel(
    const float* __restrict__ Wih, const float* __restrict__ Whh,
    const float* __restrict__ bih, const float* __restrict__ bhh,
    const float* __restrict__ W1, const float* __restrict__ W2,
    const float* __restrict__ W3, const float* __restrict__ W4,
    short* __restrict__ Wtp, float* __restrict__ bias,
    short* __restrict__ W1p, short* __restrict__ W2p,
    short* __restrict__ W3p, short* __restrict__ W4p)
{
    int idx = blockIdx.x * 256 + threadIdx.x;
    if (idx < 114688) {                     // LSTM combined [224][512]
        int j = idx & 7, L = (idx >> 3) & 63, r = idx >> 9;
        int kk = r % 7, n = r / 7;
        int k = kk * 32 + ((L >> 4) << 3) + j;
        int g = (n << 4) + (L & 15);
        float v = (k < FEAT_) ? Wih[g * FEAT_ + k] : Whh[g * H_ + (k - FEAT_)];
        float s = (n >= 16 && n < 24) ? (2.0f * L2E) : L2E;   // g gate tiles: n 16..23
        Wtp[idx] = f2bf(v * s);
        return;
    }
    int e = idx - 114688;
    if (e < 8192) {                         // W1 [25,256] * (1/255), zero-pad k>=25
        int j = e & 7, L = (e >> 3) & 63, nt = e >> 9;
        int k = ((L >> 4) << 3) + j;
        int o = nt * 16 + (L & 15);
        W1p[e] = (k < 25) ? f2bf(W1[k * 256 + o] * (1.0f / 255.0f)) : (short)0;
        return;
    }
    e -= 8192;
    if (e < 65536) {                        // W2 [256,256]
        int j = e & 7, L = (e >> 3) & 63, f = e >> 9;
        int kk = f & 7, nt = f >> 3;
        int k = kk * 32 + ((L >> 4) << 3) + j;
        W2p[e] = f2bf(W2[k * 256 + nt * 16 + (L & 15)]);
        return;
    }
    e -= 65536;
    if (e < 32768) {                        // W3 [256,128]
        int j = e & 7, L = (e >> 3) & 63, f = e >> 9;
        int kk = f & 7, nt = f >> 3;
        int k = kk * 32 + ((L >> 4) << 3) + j;
        W3p[e] = f2bf(W3[k * 128 + nt * 16 + (L & 15)]);
        return;
    }
    e -= 32768;
    if (e < 4096) {                         // W4 [128,32]
        int j = e & 7, L = (e >> 3) & 63, f = e >> 9;
        int kk = f & 3, nt = f >> 2;
        int k = kk * 32 + ((L >> 4) << 3) + j;
        W4p[e] = f2bf(W4[k * 32 + nt * 16 + (L & 15)]);
        return;
    }
    e -= 4096;
    if (e < 512) {
        float s = ((e >> 7) == 2) ? (2.0f * L2E) : L2E;       // gate 2 = g
        bias[e] = (bih[e] + bhh[e]) * s;
    }
}

// ---------------- persistent MFMA encoder: 256 blocks x 512 thr ----------------------
// loc/energy encoders folded into the prologue; ir prefetch issued right after b0.
__global__ __launch_bounds__(512, 2) void enc_kernel(
    const float* __restrict__ image,
    const float* __restrict__ location, const float* __restrict__ energy,
    const float* __restrict__ Wl, const float* __restrict__ bl,
    const float* __restrict__ We, const float* __restrict__ be,
    const short* __restrict__ W1p, const float* __restrict__ b1,
    const short* __restrict__ W2p, const float* __restrict__ b2,
    const short* __restrict__ W3p, const float* __restrict__ b3,
    const short* __restrict__ W4p, const float* __restrict__ b4,
    short* __restrict__ featsb)
{
    __shared__ float Raw[2][800];                  // raw image tile (32 samples x 25)
    __shared__ __align__(16) short In[2 * 512];    // L1 input frags [st][64][8]
    __shared__ __align__(16) short AA[2 * 8 * 512];// L1 out frags
    __shared__ __align__(16) short AB[2 * 8 * 512];// L2 out frags
    __shared__ __align__(16) short AC[2 * 4 * 512];// L3 out frags
    __shared__ float C[160];                       // Wl | bl | We | be
    const int tid  = threadIdx.x;
    const int lane = tid & 63, wv = tid >> 6;
    const int col  = lane & 15, quad = lane >> 4;

    // ---- register-resident weights & biases
    short8 w1r[2], w2r[2][8], w3r[8], w4r[4];
    #pragma unroll
    for (int i = 0; i < 2; i++)
        w1r[i] = *(const short8*)&W1p[((wv + 8 * i) * 64 + lane) * 8];
    #pragma unroll
    for (int i = 0; i < 2; i++)
        #pragma unroll
        for (int kk = 0; kk < 8; kk++)
            w2r[i][kk] = *(const short8*)&W2p[(((wv + 8 * i) * 8 + kk) * 64 + lane) * 8];
    #pragma unroll
    for (int kk = 0; kk < 8; kk++)
        w3r[kk] = *(const short8*)&W3p[((wv * 8 + kk) * 64 + lane) * 8];
    #pragma unroll
    for (int kk = 0; kk < 4; kk++)
        w4r[kk] = *(const short8*)&W4p[(((wv & 1) * 4 + kk) * 64 + lane) * 8];
    float4 b1r[2], b2r[2];
    #pragma unroll
    for (int i = 0; i < 2; i++) {
        b1r[i] = *(const float4*)(b1 + (wv + 8 * i) * 16 + quad * 4);
        b2r[i] = *(const float4*)(b2 + (wv + 8 * i) * 16 + quad * 4);
    }
    const float4 b3r = *(const float4*)(b3 + wv * 16 + quad * 4);
    const float4 b4r = *(const float4*)(b4 + (wv & 1) * 16 + quad * 4);

    // stage loc/energy const table
    if (tid < 160) {
        float v;
        if (tid < 64)       v = Wl[tid];
        else if (tid < 96)  v = bl[tid - 64];
        else if (tid < 128) v = We[tid - 96];
        else                v = be[tid - 128];
        C[tid] = v;
    }

    const bool ld = tid < 400;
    float2 ir = {0.f, 0.f};
    // prologue: Raw[0] <- tile(blockIdx); prefetch tile+256
    if (ld) {
        float2 t0 = *(const float2*)(image + (size_t)blockIdx.x * 800 + 2 * tid);
        Raw[0][2 * tid] = t0.x; Raw[0][2 * tid + 1] = t0.y;
        ir = *(const float2*)(image + (size_t)(blockIdx.x + 256) * 800 + 2 * tid);
    }
    __syncthreads();

    // ---- loc/energy for all 64 tiles of this block (feats kk=1,2) ----
    for (int q = tid; q < 2048; q += 512) {
        const int itq = q >> 5, s = q & 31;
        const int n = (itq * 256 + blockIdx.x) * 32 + s;
        const float lx = location[(size_t)n * 2 + 0] * 0.1f;
        const float ly = location[(size_t)n * 2 + 1] * 0.1f;
        const float ev = energy[n] * (1.0f / 200.0f);
        const int t = n >> 12, b = n & 4095;
        const int grp = b >> 4, bi = b & 15;
        #pragma unroll
        for (int p = 0; p < 4; p++) {
            const int kk = 1 + (p >> 1);
            #pragma unroll
            for (int o = 0; o < 2; o++) {
                const int f0 = 32 + p * 16 + o * 8;
                short8 v;
                #pragma unroll
                for (int j = 0; j < 8; j++) {
                    const int f = f0 + j;
                    float val;
                    if (f < 64) { const int cix = f - 32; val = fmaf(lx, C[cix], fmaf(ly, C[32 + cix], C[64 + cix])); }
                    else        { const int cix = f - 64; val = fmaf(ev, C[96 + cix], C[128 + cix]); }
                    v[j] = f2bf(val);
                }
                const int Lhi = ((p & 1) << 1) + o;
                *(short8*)&featsb[FBASE(t, grp, kk) + (Lhi * 16 + bi) * 8] = v;
            }
        }
    }

    // fragify In for tile 0
    {
        const int w4t = tid - 256;
        if (w4t >= 0 && w4t < 128) {
            const int st = w4t >> 6, L = w4t & 63;
            const int s = st * 16 + (L & 15), kb = (L >> 4) * 8;
            short8 v;
            #pragma unroll
            for (int j = 0; j < 8; j++) {
                const int kx = kb + j;
                v[j] = (kx < 25) ? f2bf(Raw[0][s * 25 + kx]) : (short)0;
            }
            *(short8*)&In[(st * 64 + L) * 8] = v;
        }
    }

    for (int it = 0; it < 64; it++) {
        const int nxt = (it & 1) ^ 1;
        const int tile = it * 256 + blockIdx.x;
        // stage next tile's raw
        if (ld && it + 1 < 64) { Raw[nxt][2 * tid] = ir.x; Raw[nxt][2 * tid + 1] = ir.y; }
        __syncthreads();   // b0: In(tile) + Raw[nxt] visible
        // prefetch tile+2 AFTER the barrier: in flight across the whole tile
        if (ld && it + 2 < 64)
            ir = *(const float2*)(image + (size_t)(tile + 512) * 800 + 2 * tid);

        // ---- L1: K=32 -> 256; wave owns nt {wv, wv+8}, st {0,1}
        {
            short8 bx[2];
            #pragma unroll
            for (int st = 0; st < 2; st++) bx[st] = *(const short8*)&In[(st * 64 + lane) * 8];
            #pragma unroll
            for (int i = 0; i < 2; i++) {
                const int nt = wv + 8 * i;
                #pragma unroll
                for (int st = 0; st < 2; st++) {
                    f32x4 acc = (f32x4){b1r[i].x, b1r[i].y, b1r[i].z, b1r[i].w};
                    acc = __builtin_amdgcn_mfma_f32_16x16x32_bf16(w1r[i], bx[st], acc, 0, 0, 0);
                    *(short4v*)&AA[((st * 8 + (nt >> 1)) * 64 + ((((nt & 1) << 1) + (quad >> 1)) << 4) + col) * 8 + (quad & 1) * 4]
                        = pack4relu(acc);
                }
            }
        }
        __syncthreads();   // b1

        // ---- L2: 256 -> 256 : AA -> AB
        {
            f32x4 acc[2][2];
            #pragma unroll
            for (int i = 0; i < 2; i++)
                #pragma unroll
                for (int st = 0; st < 2; st++)
                    acc[i][st] = (f32x4){b2r[i].x, b2r[i].y, b2r[i].z, b2r[i].w};
            #pragma unroll
            for (int kk = 0; kk < 8; kk++) {
                short8 bx[2];
                #pragma unroll
                for (int st = 0; st < 2; st++)
                    bx[st] = *(const short8*)&AA[((st * 8 + kk) * 64 + lane) * 8];
                #pragma unroll
                for (int i = 0; i < 2; i++)
                    #pragma unroll
                    for (int st = 0; st < 2; st++)
                        acc[i][st] = __builtin_amdgcn_mfma_f32_16x16x32_bf16(w2r[i][kk], bx[st], acc[i][st], 0, 0, 0);
            }
            #pragma unroll
            for (int i = 0; i < 2; i++) {
                const int nt = wv + 8 * i;
                #pragma unroll
                for (int st = 0; st < 2; st++)
                    *(short4v*)&AB[((st * 8 + (nt >> 1)) * 64 + ((((nt & 1) << 1) + (quad >> 1)) << 4) + col) * 8 + (quad & 1) * 4]
                        = pack4relu(acc[i][st]);
            }
        }
        __syncthreads();   // b2

        // ---- L3: 256 -> 128 : AB -> AC; wave owns nt=wv
        {
            f32x4 acc[2];
            #pragma unroll
            for (int st = 0; st < 2; st++) acc[st] = (f32x4){b3r.x, b3r.y, b3r.z, b3r.w};
            #pragma unroll
            for (int kk = 0; kk < 8; kk++) {
                #pragma unroll
                for (int st = 0; st < 2; st++) {
                    const short8 bx = *(const short8*)&AB[((st * 8 + kk) * 64 + lane) * 8];
                    acc[st] = __builtin_amdgcn_mfma_f32_16x16x32_bf16(w3r[kk], bx, acc[st], 0, 0, 0);
                }
            }
            const int nt = wv;
            #pragma unroll
            for (int st = 0; st < 2; st++)
                *(short4v*)&AC[((st * 4 + (nt >> 1)) * 64 + ((((nt & 1) << 1) + (quad >> 1)) << 4) + col) * 8 + (quad & 1) * 4]
                    = pack4relu(acc[st]);
        }
        __syncthreads();   // b3

        // ---- L4 (waves 0-3) || fragify tile it+1 (waves 4-5) — no trailing barrier
        if (wv < 4) {
            const int nt = wv & 1, st = wv >> 1;
            f32x4 acc = (f32x4){b4r.x, b4r.y, b4r.z, b4r.w};
            #pragma unroll
            for (int kk = 0; kk < 4; kk++) {
                const short8 bx = *(const short8*)&AC[((st * 4 + kk) * 64 + lane) * 8];
                acc = __builtin_amdgcn_mfma_f32_16x16x32_bf16(w4r[kk], bx, acc, 0, 0, 0);
            }
            const int t4 = tile >> 7;
            const int grp = (tile & 127) * 2 + st;
            *(short4v*)&featsb[FBASE(t4, grp, 0) + (((nt << 1) + (quad >> 1)) * 16 + col) * 8 + (quad & 1) * 4]
                = pack4relu(acc);
        } else {
            const int w4t = tid - 256;
            if (w4t >= 0 && w4t < 128 && it + 1 < 64) {
                const int st = w4t >> 6, L = w4t & 63;
                const int s = st * 16 + (L & 15), kb = (L >> 4) * 8;
                short8 v;
                #pragma unroll
                for (int j = 0; j < 8; j++) {
                    const int kx = kb + j;
                    v[j] = (kx < 25) ? f2bf(Raw[nxt][s * 25 + kx]) : (short)0;
                }
                *(short8*)&In[(st * 64 + L) * 8] = v;
            }
        }
    }
}

// ---------------- MFMA LSTM v5: 16-deep h ring, batched heads every 8 steps ----------
__global__ __launch_bounds__(512, 2) void lstm_kernel(
    const short* __restrict__ featsb, const int* __restrict__ done,
    const float* __restrict__ h0, const float* __restrict__ c0,
    const short* __restrict__ Wtp, const float* __restrict__ bias,
    const float* __restrict__ Wa, const float* __restrict__ ba,
    const float* __restrict__ Wc, const float* __restrict__ bc,
    float* __restrict__ out)
{
    __shared__ __align__(16) short Hb[16][4 * 64 * 8];  // h ring: slot t&15 = h(t) (64 KB)
    __shared__ __align__(16) short HW[4 * 64 * 8];      // head B-frags (4 KB)
    __shared__ float Ml[T_ * 16];                       // reset masks (8 KB)

    const int tid = threadIdx.x;
    const int r0 = blockIdx.x * 16;
    const int grp = r0 >> 4;
    const int lane = tid & 63;
    const int wv = tid >> 6;
    const int col = lane & 15;
    const int quad = lane >> 4;
    const int u = (wv << 4) + col;

    // register-resident LSTM weights: wave wv owns n-tiles {wv, wv+8, wv+16, wv+24}
    short8 wtr[4][7];
    #pragma unroll
    for (int g = 0; g < 4; g++)
        #pragma unroll
        for (int kk = 0; kk < 7; kk++)
            wtr[g][kk] = *(const short8*)&Wtp[((size_t)((wv + 8 * g) * 7 + kk) * 64 + lane) * 8];

    // head weight B-frags -> LDS
    for (int idx = tid; idx < 4 * 64 * 8; idx += 512) {
        int j = idx & 7, L = (idx >> 3) & 63, kk2 = idx >> 9;
        int k = kk2 * 32 + ((L >> 4) << 3) + j;
        int n = L & 15;
        float v = (n < 6) ? Wa[k * 6 + n] : (n == 6 ? Wc[k] : 0.0f);
        HW[idx] = f2bf(v);
    }
    // reset masks for all T
    for (int idx = tid; idx < T_ * 16; idx += 512)
        Ml[idx] = 1.0f - (float)done[(size_t)(idx >> 4) * B_ + r0 + (idx & 15)];

    // init: c masked by done[0]; h(-1)=h0 UNMASKED into ring slot 15
    const int kk2h = wv >> 1;
    const int Lhi_h = ((wv & 1) << 1) | (col >> 3);
    const int jh = col & 7;
    f32x4 c;
    #pragma unroll
    for (int r = 0; r < 4; r++) {
        const int s = (quad << 2) + r;
        const float m = 1.0f - (float)done[r0 + s];
        c[r] = c0[(size_t)(r0 + s) * H_ + u] * m;
        Hb[15][(kk2h * 64 + Lhi_h * 16 + s) * 8 + jh] = f2bf(h0[(size_t)(r0 + s) * H_ + u]);
    }
    const float bi0 = bias[((wv +  0) << 4) + col];
    const float bi1 = bias[((wv +  8) << 4) + col];
    const float bi2 = bias[((wv + 16) << 4) + col];
    const float bi3 = bias[((wv + 24) << 4) + col];
    const float hb = (col < 6) ? ba[col] : (col == 6 ? bc[0] : 0.0f);

    // x prefetch: two register banks (t-loop unrolled by 2)
    short8 xa[3], xb[3];
    #pragma unroll
    for (int kk = 0; kk < 3; kk++) {
        xa[kk] = *(const short8*)&featsb[FBASE(0, grp, kk) + lane * 8];
        xb[kk] = *(const short8*)&featsb[FBASE(1, grp, kk) + lane * 8];
    }
    __syncthreads();

    auto STEP = [&](int t, short8* X) {
        const int rs = (t + 15) & 15;     // slot holding h(t-1)
        const int ws = t & 15;            // slot for h(t)
        const float mcol = Ml[t * 16 + col];
        f32x4 acc0 = {bi0, bi0, bi0, bi0};
        f32x4 acc1 = {bi1, bi1, bi1, bi1};
        f32x4 acc2 = {bi2, bi2, bi2, bi2};
        f32x4 acc3 = {bi3, bi3, bi3, bi3};
        // x part (kk 0..2)
        #pragma unroll
        for (int kk = 0; kk < 3; kk++) {
            const short8 af = X[kk];
            acc0 = __builtin_amdgcn_mfma_f32_16x16x32_bf16(af, wtr[0][kk], acc0, 0, 0, 0);
            acc1 = __builtin_amdgcn_mfma_f32_16x16x32_bf16(af, wtr[1][kk], acc1, 0, 0, 0);
            acc2 = __builtin_amdgcn_mfma_f32_16x16x32_bf16(af, wtr[2][kk], acc2, 0, 0, 0);
            acc3 = __builtin_amdgcn_mfma_f32_16x16x32_bf16(af, wtr[3][kk], acc3, 0, 0, 0);
        }
        // bank consumed -> reload for t+2 NOW (max distance to any drain point)
        if (t + 2 < T_) {
            #pragma unroll
            for (int kk = 0; kk < 3; kk++)
                X[kk] = *(const short8*)&featsb[FBASE(t + 2, grp, kk) + lane * 8];
        }
        // h part (kk 3..6), reset mask applied per-lane (m in {0,1} -> exact)
        #pragma unroll
        for (int kk = 3; kk < 7; kk++) {
            short8 af = *(const short8*)&Hb[rs][((kk - 3) * 64 + lane) * 8];
            if (mcol == 0.0f) af = (short8){0,0,0,0,0,0,0,0};
            acc0 = __builtin_amdgcn_mfma_f32_16x16x32_bf16(af, wtr[0][kk], acc0, 0, 0, 0);
            acc1 = __builtin_amdgcn_mfma_f32_16x16x32_bf16(af, wtr[1][kk], acc1, 0, 0, 0);
            acc2 = __builtin_amdgcn_mfma_f32_16x16x32_bf16(af, wtr[2][kk], acc2, 0, 0, 0);
            acc3 = __builtin_amdgcn_mfma_f32_16x16x32_bf16(af, wtr[3][kk], acc3, 0, 0, 0);
        }
        // cell update (gates pre-scaled by log2e / 2log2e); h stored UNMASKED
        float4 mn = {1.f, 1.f, 1.f, 1.f};
        if (t < T_ - 1) mn = *(const float4*)&Ml[(t + 1) * 16 + (quad << 2)];
        #pragma unroll
        for (int r = 0; r < 4; r++) {
            const float ig = sig2(acc0[r]);
            const float fg = sig2(acc1[r]);
            const float gt = fmaf(2.0f, sig2(acc2[r]), -1.0f);
            const float og = sig2(acc3[r]);
            const float cn = fmaf(fg, c[r], ig * gt);
            const float h = og * ftanh(cn);
            c[r] = cn * ((&mn.x)[r]);
            Hb[ws][(kk2h * 64 + Lhi_h * 16 + (quad << 2) + r) * 8 + jh] = f2bf(h);
        }
        __syncthreads();

        // batched heads: every 8th step, ALL waves do one step's heads in parallel
        if ((t & 7) == 7) {
            const int tp = t - 7 + wv;
            const int sp = tp & 15;
            f32x4 ha = {hb, hb, hb, hb};
            #pragma unroll
            for (int kk2 = 0; kk2 < 4; kk2++) {
                const short8 hf = *(const short8*)&Hb[sp][(kk2 * 64 + lane) * 8];
                const short8 wf = *(const short8*)&HW[(kk2 * 64 + lane) * 8];
                ha = __builtin_amdgcn_mfma_f32_16x16x32_bf16(hf, wf, ha, 0, 0, 0);
            }
            if (col < 7) {
                #pragma unroll
                for (int r = 0; r < 4; r++) {
                    const int s = (quad << 2) + r;
                    out[((size_t)tp * B_ + r0 + s) * 7 + col] = ha[r];
                }
            }
        }
    };

    for (int t = 0; t < T_; t += 2) {
        STEP(t, xa);
        STEP(t + 1, xb);
    }
}

extern "C" void kernel_launch(void* const* d_in, const int* in_sizes, int n_in,
                              void* d_out, int out_size, void* d_ws, size_t ws_size,
                              hipStream_t stream) {
    const float* image    = (const float*)d_in[0];
    const float* location = (const float*)d_in[1];
    const float* energy   = (const float*)d_in[2];
    const int*   done     = (const int*)d_in[3];
    const float* h0       = (const float*)d_in[4];
    const float* c0       = (const float*)d_in[5];
    const float* W1 = (const float*)d_in[6];   const float* b1 = (const float*)d_in[7];
    const float* W2 = (const float*)d_in[8];   const float* b2 = (const float*)d_in[9];
    const float* W3 = (const float*)d_in[10];  const float* b3 = (const float*)d_in[11];
    const float* W4 = (const float*)d_in[12];  const float* b4 = (const float*)d_in[13];
    const float* Wl = (const float*)d_in[14];  const float* bl = (const float*)d_in[15];
    const float* We = (const float*)d_in[16];  const float* be = (const float*)d_in[17];
    const float* Wih = (const float*)d_in[18]; const float* Whh = (const float*)d_in[19];
    const float* bih = (const float*)d_in[20]; const float* bhh = (const float*)d_in[21];
    const float* Wa = (const float*)d_in[22];  const float* ba = (const float*)d_in[23];
    const float* Wc = (const float*)d_in[24];  const float* bc = (const float*)d_in[25];

    char* ws = (char*)d_ws;
    short* Wtp   = (short*)ws;                     // 229376 B
    float* bias  = (float*)(ws + 229376);          // 2048 B
    short* W1p   = (short*)(ws + 231424);          // 16384 B
    short* W2p   = (short*)(ws + 247808);          // 131072 B
    short* W3p   = (short*)(ws + 378880);          // 65536 B
    short* W4p   = (short*)(ws + 444416);          // 8192 B
    short* featsb = (short*)(ws + 452608);         // N*96 bf16 (frag order)
    float* out   = (float*)d_out;

    prep_kernel<<<882, 256, 0, stream>>>(Wih, Whh, bih, bhh, W1, W2, W3, W4,
                                         Wtp, bias, W1p, W2p, W3p, W4p);
    enc_kernel<<<256, 512, 0, stream>>>(image, location, energy, Wl, bl, We, be,
                                        W1p, b1, W2p, b2, W3p, b3, W4p, b4, featsb);
    lstm_kernel<<<B_ / 16, 512, 0, stream>>>(featsb, done, h0, c0, Wtp, bias,
                                             Wa, ba, Wc, bc, out);
}